// Round 1
// baseline (302.130 us; speedup 1.0000x reference)
//
#include <hip/hip_runtime.h>
#include <hip/hip_bf16.h>

typedef __attribute__((ext_vector_type(8))) __bf16 bf16x8;
typedef __attribute__((ext_vector_type(4))) float f32x4;

#define MFMA16(a, b, c) __builtin_amdgcn_mfma_f32_16x16x32_bf16((a), (b), (c), 0, 0, 0)

static constexpr int DM = 1024;
static constexpr int SEQ = 2048;
static constexpr int NB = 2;
static constexpr int NH = 16;
static constexpr int DKK = 64;
static constexpr int MROWS = NB * SEQ;  // 4096

// ---------------- Projection GEMM ----------------
// Y[b,h,s,dk] (bf16, ws) = sum_d X[b*S+s][d] * W[e][d],  e = h*64+dk
// X: (4096,1024) f32 row-major, W: (1024,1024) f32 row-major (K contiguous).
__global__ __launch_bounds__(256) void proj_gemm_kernel(
    const float* __restrict__ X, const float* __restrict__ W,
    __bf16* __restrict__ Y) {
  __shared__ __bf16 As[128][40];
  __shared__ __bf16 Bs[128][40];
  const int tid = threadIdx.x;
  const int lane = tid & 63;
  const int wv = tid >> 6;
  const int wm = (wv >> 1) * 64;
  const int wn = (wv & 1) * 64;
  const int bm = blockIdx.y * 128;
  const int bn = blockIdx.x * 128;
  const int g = lane >> 4, c = lane & 15;
  const int srow = tid >> 1;          // 0..127
  const int shalf = (tid & 1) * 16;   // 0 or 16
  f32x4 acc[4][4] = {};
  const float* ap0 = X + (size_t)(bm + srow) * DM + shalf;
  const float* bp0 = W + (size_t)(bn + srow) * DM + shalf;
  for (int k0 = 0; k0 < DM; k0 += 32) {
    f32x4 xa[4], xb[4];
#pragma unroll
    for (int i = 0; i < 4; ++i) {
      xa[i] = *(const f32x4*)(ap0 + k0 + i * 4);
      xb[i] = *(const f32x4*)(bp0 + k0 + i * 4);
    }
    bf16x8 ha[2], hb[2];
#pragma unroll
    for (int i = 0; i < 2; ++i)
#pragma unroll
      for (int j = 0; j < 8; ++j) {
        ha[i][j] = (__bf16)xa[i * 2 + (j >> 2)][j & 3];
        hb[i][j] = (__bf16)xb[i * 2 + (j >> 2)][j & 3];
      }
    *(bf16x8*)&As[srow][shalf] = ha[0];
    *(bf16x8*)&As[srow][shalf + 8] = ha[1];
    *(bf16x8*)&Bs[srow][shalf] = hb[0];
    *(bf16x8*)&Bs[srow][shalf + 8] = hb[1];
    __syncthreads();
    bf16x8 af[4], bfr[4];
#pragma unroll
    for (int i = 0; i < 4; ++i) {
      af[i] = *(const bf16x8*)&As[wm + i * 16 + c][g * 8];
      bfr[i] = *(const bf16x8*)&Bs[wn + i * 16 + c][g * 8];
    }
#pragma unroll
    for (int mi = 0; mi < 4; ++mi)
#pragma unroll
      for (int ni = 0; ni < 4; ++ni)
        acc[mi][ni] = MFMA16(af[mi], bfr[ni], acc[mi][ni]);
    __syncthreads();
  }
#pragma unroll
  for (int mi = 0; mi < 4; ++mi)
#pragma unroll
    for (int ni = 0; ni < 4; ++ni)
#pragma unroll
      for (int r = 0; r < 4; ++r) {
        const int row = bm + wm + mi * 16 + g * 4 + r;
        const int col = bn + wn + ni * 16 + c;
        const int b = row >> 11;
        const int s = row & (SEQ - 1);
        const int h = col >> 6;
        const int dk = col & 63;
        Y[((size_t)((b * NH + h) * SEQ + s) << 6) + dk] = (__bf16)acc[mi][ni][r];
      }
}

// ---------------- Output GEMM ----------------
// Y[row][col] (f32) = sum_d X[row][d] * W[col][d];  X bf16 (attn out), W f32 (Wo)
__global__ __launch_bounds__(256) void out_gemm_kernel(
    const __bf16* __restrict__ X, const float* __restrict__ W,
    float* __restrict__ Y) {
  __shared__ __bf16 As[128][40];
  __shared__ __bf16 Bs[128][40];
  const int tid = threadIdx.x;
  const int lane = tid & 63;
  const int wv = tid >> 6;
  const int wm = (wv >> 1) * 64;
  const int wn = (wv & 1) * 64;
  const int bm = blockIdx.y * 128;
  const int bn = blockIdx.x * 128;
  const int g = lane >> 4, c = lane & 15;
  const int srow = tid >> 1;
  const int shalf = (tid & 1) * 16;
  f32x4 acc[4][4] = {};
  const __bf16* xp0 = X + (size_t)(bm + srow) * DM + shalf;
  const float* bp0 = W + (size_t)(bn + srow) * DM + shalf;
  for (int k0 = 0; k0 < DM; k0 += 32) {
    bf16x8 ha0 = *(const bf16x8*)(xp0 + k0);
    bf16x8 ha1 = *(const bf16x8*)(xp0 + k0 + 8);
    f32x4 xb[4];
#pragma unroll
    for (int i = 0; i < 4; ++i) xb[i] = *(const f32x4*)(bp0 + k0 + i * 4);
    bf16x8 hb[2];
#pragma unroll
    for (int i = 0; i < 2; ++i)
#pragma unroll
      for (int j = 0; j < 8; ++j) hb[i][j] = (__bf16)xb[i * 2 + (j >> 2)][j & 3];
    *(bf16x8*)&As[srow][shalf] = ha0;
    *(bf16x8*)&As[srow][shalf + 8] = ha1;
    *(bf16x8*)&Bs[srow][shalf] = hb[0];
    *(bf16x8*)&Bs[srow][shalf + 8] = hb[1];
    __syncthreads();
    bf16x8 af[4], bfr[4];
#pragma unroll
    for (int i = 0; i < 4; ++i) {
      af[i] = *(const bf16x8*)&As[wm + i * 16 + c][g * 8];
      bfr[i] = *(const bf16x8*)&Bs[wn + i * 16 + c][g * 8];
    }
#pragma unroll
    for (int mi = 0; mi < 4; ++mi)
#pragma unroll
      for (int ni = 0; ni < 4; ++ni)
        acc[mi][ni] = MFMA16(af[mi], bfr[ni], acc[mi][ni]);
    __syncthreads();
  }
#pragma unroll
  for (int mi = 0; mi < 4; ++mi)
#pragma unroll
    for (int ni = 0; ni < 4; ++ni)
#pragma unroll
      for (int r = 0; r < 4; ++r) {
        const int row = bm + wm + mi * 16 + g * 4 + r;
        const int col = bn + wn + ni * 16 + c;
        Y[(size_t)row * DM + col] = acc[mi][ni][r];
      }
}

// ---------------- Causal flash attention ----------------
// Q,K,V: (B,H,S,64) bf16.  O: (B,S,1024) bf16.
// Block: 256 thr (4 waves), 64 Q-rows per block (16 per wave), KV tile 64.
__global__ __launch_bounds__(256) void attn_kernel(
    const __bf16* __restrict__ Qw, const __bf16* __restrict__ Kw,
    const __bf16* __restrict__ Vw, __bf16* __restrict__ Ow) {
  __shared__ __bf16 Ks[64][72];        // [kv][d], +8 pad
  __shared__ __bf16 Vt[64][72];        // [d][kv ^ 8*(d>>3)] swizzled transpose
  __shared__ __bf16 Pl[4][16][72];     // per-wave P tile [qrow][kv]
  const int tid = threadIdx.x;
  const int lane = tid & 63;
  const int wv = tid >> 6;
  const int g = lane >> 4, c = lane & 15;
  const int qt = blockIdx.x;           // 0..31 (q tile)
  const int bh = blockIdx.y;           // 0..31 (b*16+h)
  const size_t base = (size_t)bh * SEQ * DKK;
  const int qrow0 = qt * 64 + wv * 16;
  bf16x8 qf0, qf1;
  {
    const __bf16* qp = Qw + base + (size_t)(qrow0 + c) * DKK + g * 8;
    qf0 = *(const bf16x8*)qp;
    qf1 = *(const bf16x8*)(qp + 32);
  }
  f32x4 oacc[4] = {};
  float m_r[4], l_r[4];
#pragma unroll
  for (int r = 0; r < 4; ++r) { m_r[r] = -3e38f; l_r[r] = 0.f; }
  const int srow = tid >> 3;           // 0..31
  const int sseg = (tid & 7) * 8;      // 0..56
  for (int t = 0; t <= qt; ++t) {
    const int kv0 = t * 64;
#pragma unroll
    for (int pass = 0; pass < 2; ++pass) {
      const int row = srow + pass * 32;
      const size_t goff = base + (size_t)(kv0 + row) * DKK + sseg;
      *(bf16x8*)&Ks[row][sseg] = *(const bf16x8*)(Kw + goff);
      bf16x8 vvec = *(const bf16x8*)(Vw + goff);
      const int vcol = row ^ sseg;     // row ^ (8*(d>>3)), d>>3 == sseg/8
#pragma unroll
      for (int j = 0; j < 8; ++j) Vt[sseg + j][vcol] = vvec[j];
    }
    __syncthreads();
    // S = Q K^T  (per wave: 16 q-rows x 64 kv-cols)
    f32x4 sac[4] = {};
#pragma unroll
    for (int cb = 0; cb < 4; ++cb) {
      bf16x8 kb0 = *(const bf16x8*)&Ks[cb * 16 + c][g * 8];
      bf16x8 kb1 = *(const bf16x8*)&Ks[cb * 16 + c][32 + g * 8];
      sac[cb] = MFMA16(qf0, kb0, sac[cb]);
      sac[cb] = MFMA16(qf1, kb1, sac[cb]);
    }
    // online softmax (rows = g*4+r, cols = cb*16+c); reduce over c via shfl
    const float scl = 0.125f * 1.44269504f;  // 1/sqrt(64) * log2(e)
#pragma unroll
    for (int r = 0; r < 4; ++r) {
      const int qg = qrow0 + g * 4 + r;
      float sv[4];
      float mx = -3e38f;
#pragma unroll
      for (int cb = 0; cb < 4; ++cb) {
        float x = sac[cb][r] * scl;
        if (kv0 + cb * 16 + c > qg) x = -3e38f;
        sv[cb] = x;
        mx = fmaxf(mx, x);
      }
#pragma unroll
      for (int o = 1; o < 16; o <<= 1) mx = fmaxf(mx, __shfl_xor(mx, o, 64));
      const float mn = fmaxf(m_r[r], mx);
      const float al = exp2f(m_r[r] - mn);
      m_r[r] = mn;
      float rs = 0.f;
#pragma unroll
      for (int cb = 0; cb < 4; ++cb) {
        const float p = exp2f(sv[cb] - mn);
        rs += p;
        Pl[wv][g * 4 + r][cb * 16 + c] = (__bf16)p;
      }
#pragma unroll
      for (int o = 1; o < 16; o <<= 1) rs += __shfl_xor(rs, o, 64);
      l_r[r] = l_r[r] * al + rs;
#pragma unroll
      for (int ob = 0; ob < 4; ++ob) oacc[ob][r] *= al;
    }
    // O += P V  (wave-private P round-trip; same-wave LDS order is safe)
    const bf16x8 pa0 = *(const bf16x8*)&Pl[wv][c][g * 8];
    const bf16x8 pa1 = *(const bf16x8*)&Pl[wv][c][32 + g * 8];
#pragma unroll
    for (int ob = 0; ob < 4; ++ob) {
      const int d = ob * 16 + c;
      const int hi = d >> 3;
      const bf16x8 vb0 = *(const bf16x8*)&Vt[d][((0 + g) ^ hi) * 8];
      const bf16x8 vb1 = *(const bf16x8*)&Vt[d][((4 + g) ^ hi) * 8];
      oacc[ob] = MFMA16(pa0, vb0, oacc[ob]);
      oacc[ob] = MFMA16(pa1, vb1, oacc[ob]);
    }
    __syncthreads();
  }
  const int b = bh >> 4, h = bh & 15;
#pragma unroll
  for (int ob = 0; ob < 4; ++ob)
#pragma unroll
    for (int r = 0; r < 4; ++r) {
      const int qg = qrow0 + g * 4 + r;
      const float val = oacc[ob][r] / l_r[r];
      Ow[(size_t)(b * SEQ + qg) * DM + h * 64 + ob * 16 + c] = (__bf16)val;
    }
}

extern "C" void kernel_launch(void* const* d_in, const int* in_sizes, int n_in,
                              void* d_out, int out_size, void* d_ws,
                              size_t ws_size, hipStream_t stream) {
  const float* q = (const float*)d_in[0];
  const float* k = (const float*)d_in[1];
  const float* v = (const float*)d_in[2];
  // d_in[3] = mask (tril) — causality is hard-coded in attn_kernel
  const float* Wq = (const float*)d_in[4];
  const float* Wk = (const float*)d_in[5];
  const float* Wv = (const float*)d_in[6];
  const float* Wo = (const float*)d_in[7];
  __bf16* ws = (__bf16*)d_ws;
  const size_t SZ = (size_t)NB * NH * SEQ * DKK;  // 4,194,304 elems
  __bf16* qws = ws;
  __bf16* kws = ws + SZ;
  __bf16* vws = ws + 2 * SZ;
  __bf16* ows = ws + 3 * SZ;
  dim3 gemm_grid(DM / 128, MROWS / 128);  // (8, 32)
  proj_gemm_kernel<<<gemm_grid, 256, 0, stream>>>(q, Wq, qws);
  proj_gemm_kernel<<<gemm_grid, 256, 0, stream>>>(k, Wk, kws);
  proj_gemm_kernel<<<gemm_grid, 256, 0, stream>>>(v, Wv, vws);
  attn_kernel<<<dim3(SEQ / 64, NB * NH), 256, 0, stream>>>(qws, kws, vws, ows);
  out_gemm_kernel<<<gemm_grid, 256, 0, stream>>>(ows, Wo, (float*)d_out);
}

// Round 2
// 212.221 us; speedup vs baseline: 1.4237x; 1.4237x over previous
//
#include <hip/hip_runtime.h>
#include <hip/hip_bf16.h>

typedef __attribute__((ext_vector_type(8))) __bf16 bf16x8;
typedef __attribute__((ext_vector_type(4))) __bf16 bf16x4;
typedef __attribute__((ext_vector_type(4))) float f32x4;

#define MFMA16(a, b, c) __builtin_amdgcn_mfma_f32_16x16x32_bf16((a), (b), (c), 0, 0, 0)

static constexpr int DM = 1024;
static constexpr int SEQ = 2048;
static constexpr int NB = 2;
static constexpr int NH = 16;
static constexpr int DKK = 64;
static constexpr int MROWS = NB * SEQ;  // 4096

// ---------------- Fused Q/K/V projection GEMM (z selects which) ----------------
// Y[b,h,s,dk] (bf16, ws) = sum_d X[b*S+s][d] * W[e][d],  e = h*64+dk
__global__ __launch_bounds__(256) void proj3_kernel(
    const float* __restrict__ Xq, const float* __restrict__ Xk,
    const float* __restrict__ Xv, const float* __restrict__ Wq,
    const float* __restrict__ Wk, const float* __restrict__ Wv,
    __bf16* __restrict__ Yq, __bf16* __restrict__ Yk, __bf16* __restrict__ Yv) {
  __shared__ __bf16 As[128][40];
  __shared__ __bf16 Bs[128][40];
  const int z = blockIdx.z;
  const float* X = (z == 0) ? Xq : (z == 1) ? Xk : Xv;
  const float* W = (z == 0) ? Wq : (z == 1) ? Wk : Wv;
  __bf16* Y = (z == 0) ? Yq : (z == 1) ? Yk : Yv;
  const int tid = threadIdx.x;
  const int lane = tid & 63;
  const int wv = tid >> 6;
  const int wm = (wv >> 1) * 64;
  const int wn = (wv & 1) * 64;
  const int bm = blockIdx.y * 128;
  const int bn = blockIdx.x * 128;
  const int g = lane >> 4, c = lane & 15;
  const int srow = tid >> 1;          // 0..127
  const int shalf = (tid & 1) * 16;   // 0 or 16
  f32x4 acc[4][4] = {};
  const float* ap0 = X + (size_t)(bm + srow) * DM + shalf;
  const float* bp0 = W + (size_t)(bn + srow) * DM + shalf;
  for (int k0 = 0; k0 < DM; k0 += 32) {
    f32x4 xa[4], xb[4];
#pragma unroll
    for (int i = 0; i < 4; ++i) {
      xa[i] = *(const f32x4*)(ap0 + k0 + i * 4);
      xb[i] = *(const f32x4*)(bp0 + k0 + i * 4);
    }
    bf16x8 ha[2], hb[2];
#pragma unroll
    for (int i = 0; i < 2; ++i)
#pragma unroll
      for (int j = 0; j < 8; ++j) {
        ha[i][j] = (__bf16)xa[i * 2 + (j >> 2)][j & 3];
        hb[i][j] = (__bf16)xb[i * 2 + (j >> 2)][j & 3];
      }
    *(bf16x8*)&As[srow][shalf] = ha[0];
    *(bf16x8*)&As[srow][shalf + 8] = ha[1];
    *(bf16x8*)&Bs[srow][shalf] = hb[0];
    *(bf16x8*)&Bs[srow][shalf + 8] = hb[1];
    __syncthreads();
    bf16x8 af[4], bfr[4];
#pragma unroll
    for (int i = 0; i < 4; ++i) {
      af[i] = *(const bf16x8*)&As[wm + i * 16 + c][g * 8];
      bfr[i] = *(const bf16x8*)&Bs[wn + i * 16 + c][g * 8];
    }
#pragma unroll
    for (int mi = 0; mi < 4; ++mi)
#pragma unroll
      for (int ni = 0; ni < 4; ++ni)
        acc[mi][ni] = MFMA16(af[mi], bfr[ni], acc[mi][ni]);
    __syncthreads();
  }
#pragma unroll
  for (int mi = 0; mi < 4; ++mi)
#pragma unroll
    for (int ni = 0; ni < 4; ++ni)
#pragma unroll
      for (int r = 0; r < 4; ++r) {
        const int row = bm + wm + mi * 16 + g * 4 + r;
        const int col = bn + wn + ni * 16 + c;
        const int b = row >> 11;
        const int s = row & (SEQ - 1);
        const int h = col >> 6;
        const int dk = col & 63;
        Y[((size_t)((b * NH + h) * SEQ + s) << 6) + dk] = (__bf16)acc[mi][ni][r];
      }
}

// ---------------- Output GEMM ----------------
__global__ __launch_bounds__(256) void out_gemm_kernel(
    const __bf16* __restrict__ X, const float* __restrict__ W,
    float* __restrict__ Y) {
  __shared__ __bf16 As[128][40];
  __shared__ __bf16 Bs[128][40];
  const int tid = threadIdx.x;
  const int lane = tid & 63;
  const int wv = tid >> 6;
  const int wm = (wv >> 1) * 64;
  const int wn = (wv & 1) * 64;
  const int bm = blockIdx.y * 128;
  const int bn = blockIdx.x * 128;
  const int g = lane >> 4, c = lane & 15;
  const int srow = tid >> 1;
  const int shalf = (tid & 1) * 16;
  f32x4 acc[4][4] = {};
  const __bf16* xp0 = X + (size_t)(bm + srow) * DM + shalf;
  const float* bp0 = W + (size_t)(bn + srow) * DM + shalf;
  for (int k0 = 0; k0 < DM; k0 += 32) {
    bf16x8 ha0 = *(const bf16x8*)(xp0 + k0);
    bf16x8 ha1 = *(const bf16x8*)(xp0 + k0 + 8);
    f32x4 xb[4];
#pragma unroll
    for (int i = 0; i < 4; ++i) xb[i] = *(const f32x4*)(bp0 + k0 + i * 4);
    bf16x8 hb[2];
#pragma unroll
    for (int i = 0; i < 2; ++i)
#pragma unroll
      for (int j = 0; j < 8; ++j) hb[i][j] = (__bf16)xb[i * 2 + (j >> 2)][j & 3];
    *(bf16x8*)&As[srow][shalf] = ha0;
    *(bf16x8*)&As[srow][shalf + 8] = ha1;
    *(bf16x8*)&Bs[srow][shalf] = hb[0];
    *(bf16x8*)&Bs[srow][shalf + 8] = hb[1];
    __syncthreads();
    bf16x8 af[4], bfr[4];
#pragma unroll
    for (int i = 0; i < 4; ++i) {
      af[i] = *(const bf16x8*)&As[wm + i * 16 + c][g * 8];
      bfr[i] = *(const bf16x8*)&Bs[wn + i * 16 + c][g * 8];
    }
#pragma unroll
    for (int mi = 0; mi < 4; ++mi)
#pragma unroll
      for (int ni = 0; ni < 4; ++ni)
        acc[mi][ni] = MFMA16(af[mi], bfr[ni], acc[mi][ni]);
    __syncthreads();
  }
#pragma unroll
  for (int mi = 0; mi < 4; ++mi)
#pragma unroll
    for (int ni = 0; ni < 4; ++ni)
#pragma unroll
      for (int r = 0; r < 4; ++r) {
        const int row = bm + wm + mi * 16 + g * 4 + r;
        const int col = bn + wn + ni * 16 + c;
        Y[(size_t)row * DM + col] = acc[mi][ni][r];
      }
}

// ---------------- Causal flash attention (swapped-QK^T, reg-prefetch) --------
// Q,K,V: (B,H,S,64) bf16.  O: (B,S,1024) bf16.
// 256 thr (4 waves); 64 Q-rows/block (16/wave, one q per lane col); KV tile 64.
// Swapped: S^T = K·Q^T so lane (g,c) holds S[q=c][kv=m*16+g*4+r] -> row softmax
// is in-lane + 2 shfls. O^T = V^T·P^T so rescale is a per-lane scalar mul.
__global__ __launch_bounds__(256) void attn_kernel(
    const __bf16* __restrict__ Qw, const __bf16* __restrict__ Kw,
    const __bf16* __restrict__ Vw, __bf16* __restrict__ Ow) {
  __shared__ __bf16 Ks[64][72];        // [kv][d], +8 pad
  __shared__ __bf16 Vt[64][72];        // [d][kv ^ 8*(d>>3)] swizzled transpose
  __shared__ __bf16 Pl[4][16][72];     // per-wave P [q][kv]
  const int tid = threadIdx.x;
  const int lane = tid & 63;
  const int wv = tid >> 6;
  const int g = lane >> 4, c = lane & 15;
  const int qt = (gridDim.x - 1) - blockIdx.x;  // heavy blocks dispatch first
  const int bh = blockIdx.y;                    // b*16+h
  const size_t base = (size_t)bh * SEQ * DKK;
  const int qrow0 = qt * 64 + wv * 16;
  bf16x8 qf0, qf1;
  {
    const __bf16* qp = Qw + base + (size_t)(qrow0 + c) * DKK + g * 8;
    qf0 = *(const bf16x8*)qp;
    qf1 = *(const bf16x8*)(qp + 32);
  }
  f32x4 oacc[4] = {};
  float m_r = -3e38f, l_r = 0.f;
  const int srow = tid >> 3;           // 0..31
  const int sseg = (tid & 7) * 8;      // 0..56
  // prologue: prefetch tile 0 into registers
  bf16x8 kreg[2], vreg[2];
#pragma unroll
  for (int pass = 0; pass < 2; ++pass) {
    const size_t goff = base + (size_t)(srow + pass * 32) * DKK + sseg;
    kreg[pass] = *(const bf16x8*)(Kw + goff);
    vreg[pass] = *(const bf16x8*)(Vw + goff);
  }
  for (int t = 0; t <= qt; ++t) {
    // write staged regs -> LDS (prev iteration's trailing barrier protects)
#pragma unroll
    for (int pass = 0; pass < 2; ++pass) {
      const int row = srow + pass * 32;
      *(bf16x8*)&Ks[row][sseg] = kreg[pass];
      const int vcol = row ^ sseg;     // row ^ (8*(d>>3))
#pragma unroll
      for (int j = 0; j < 8; ++j) Vt[sseg + j][vcol] = vreg[pass][j];
    }
    __syncthreads();
    // prefetch tile t+1 (latency hides under compute below)
    if (t < qt) {
      const int kv1 = (t + 1) * 64;
#pragma unroll
      for (int pass = 0; pass < 2; ++pass) {
        const size_t goff = base + (size_t)(kv1 + srow + pass * 32) * DKK + sseg;
        kreg[pass] = *(const bf16x8*)(Kw + goff);
        vreg[pass] = *(const bf16x8*)(Vw + goff);
      }
    }
    // S^T = K·Q^T : sac[m] holds S[q=c][kv = m*16 + g*4 + r]
    f32x4 sac[4];
#pragma unroll
    for (int m = 0; m < 4; ++m) {
      bf16x8 kb0 = *(const bf16x8*)&Ks[m * 16 + c][g * 8];
      bf16x8 kb1 = *(const bf16x8*)&Ks[m * 16 + c][32 + g * 8];
      f32x4 zz = {};
      zz = MFMA16(kb0, qf0, zz);
      sac[m] = MFMA16(kb1, qf1, zz);
    }
    const float scl = 0.125f * 1.44269504f;  // 1/sqrt(64) * log2(e)
    float sv[16];
    float mx = -3e38f;
    if (t == qt) {  // only the diagonal tile needs masking
#pragma unroll
      for (int m = 0; m < 4; ++m)
#pragma unroll
        for (int r = 0; r < 4; ++r) {
          float x = sac[m][r] * scl;
          if (m * 16 + g * 4 + r > wv * 16 + c) x = -3e38f;
          sv[m * 4 + r] = x;
          mx = fmaxf(mx, x);
        }
    } else {
#pragma unroll
      for (int m = 0; m < 4; ++m)
#pragma unroll
        for (int r = 0; r < 4; ++r) {
          float x = sac[m][r] * scl;
          sv[m * 4 + r] = x;
          mx = fmaxf(mx, x);
        }
    }
    mx = fmaxf(mx, __shfl_xor(mx, 16, 64));
    mx = fmaxf(mx, __shfl_xor(mx, 32, 64));
    const float mn = fmaxf(m_r, mx);
    const float al = exp2f(m_r - mn);
    m_r = mn;
    float rs = 0.f;
#pragma unroll
    for (int m = 0; m < 4; ++m) {
      bf16x4 pq;
#pragma unroll
      for (int r = 0; r < 4; ++r) {
        const float p = exp2f(sv[m * 4 + r] - mn);
        rs += p;
        pq[r] = (__bf16)p;
      }
      *(bf16x4*)&Pl[wv][c][m * 16 + g * 4] = pq;  // P[q=c][kv], packed b64
    }
    rs += __shfl_xor(rs, 16, 64);
    rs += __shfl_xor(rs, 32, 64);
    l_r = l_r * al + rs;
#pragma unroll
    for (int ob = 0; ob < 4; ++ob)
#pragma unroll
      for (int r = 0; r < 4; ++r) oacc[ob][r] *= al;
    // O^T += V^T·P^T : oacc[ob] holds O[q=c][d = ob*16 + g*4 + r]
    const bf16x8 pf0 = *(const bf16x8*)&Pl[wv][c][g * 8];
    const bf16x8 pf1 = *(const bf16x8*)&Pl[wv][c][32 + g * 8];
#pragma unroll
    for (int ob = 0; ob < 4; ++ob) {
      const int d = ob * 16 + c;
      const int hi = d >> 3;
      const bf16x8 vb0 = *(const bf16x8*)&Vt[d][((0 + g) ^ hi) * 8];
      const bf16x8 vb1 = *(const bf16x8*)&Vt[d][((4 + g) ^ hi) * 8];
      oacc[ob] = MFMA16(vb0, pf0, oacc[ob]);
      oacc[ob] = MFMA16(vb1, pf1, oacc[ob]);
    }
    __syncthreads();
  }
  const int b = bh >> 4, h = bh & 15;
  const int q = qrow0 + c;
  const float inv = 1.0f / l_r;
#pragma unroll
  for (int ob = 0; ob < 4; ++ob) {
    bf16x4 st;
#pragma unroll
    for (int r = 0; r < 4; ++r) st[r] = (__bf16)(oacc[ob][r] * inv);
    *(bf16x4*)&Ow[(size_t)(b * SEQ + q) * DM + h * 64 + ob * 16 + g * 4] = st;
  }
}

extern "C" void kernel_launch(void* const* d_in, const int* in_sizes, int n_in,
                              void* d_out, int out_size, void* d_ws,
                              size_t ws_size, hipStream_t stream) {
  const float* q = (const float*)d_in[0];
  const float* k = (const float*)d_in[1];
  const float* v = (const float*)d_in[2];
  // d_in[3] = mask (tril) — causality is hard-coded in attn_kernel
  const float* Wq = (const float*)d_in[4];
  const float* Wk = (const float*)d_in[5];
  const float* Wv = (const float*)d_in[6];
  const float* Wo = (const float*)d_in[7];
  __bf16* ws = (__bf16*)d_ws;
  const size_t SZ = (size_t)NB * NH * SEQ * DKK;  // 4,194,304 elems
  __bf16* qws = ws;
  __bf16* kws = ws + SZ;
  __bf16* vws = ws + 2 * SZ;
  __bf16* ows = ws + 3 * SZ;
  proj3_kernel<<<dim3(DM / 128, MROWS / 128, 3), 256, 0, stream>>>(
      q, k, v, Wq, Wk, Wv, qws, kws, vws);
  attn_kernel<<<dim3(SEQ / 64, NB * NH), 256, 0, stream>>>(qws, kws, vws, ows);
  out_gemm_kernel<<<dim3(DM / 128, MROWS / 128), 256, 0, stream>>>(
      ows, Wo, (float*)d_out);
}